// Round 2
// baseline (809.765 us; speedup 1.0000x reference)
//
#include <hip/hip_runtime.h>
#include <hip/hip_bf16.h>
#include <stdint.h>

#define BB 8
#define SS 2048
#define DD 1024
#define KREAL 204
#define KP 256

typedef __attribute__((ext_vector_type(8))) short short8;
typedef __attribute__((ext_vector_type(4))) float floatx4;
typedef uint16_t u16;
typedef uint32_t u32;

__device__ __forceinline__ float bf2f(u16 u) {
    union { float f; u32 i; } c; c.i = ((u32)u) << 16; return c.f;
}
__device__ __forceinline__ u16 f2bf(float f) {
    union { float f; u32 i; } c; c.f = f;
    u32 i = c.i;
    u32 r = (i + 0x7FFFu + ((i >> 16) & 1u)) >> 16;
    return (u16)r;
}

union V16 { uint4 u; short8 s8; u16 h[8]; };

// ---------------------------------------------------------------------------
// Cast f32 -> bf16, 4 elements per thread.
// ---------------------------------------------------------------------------
__global__ __launch_bounds__(256) void k_cast_bf16(
    const float* __restrict__ x, u16* __restrict__ o) {
    size_t i = ((size_t)blockIdx.x * 256 + threadIdx.x) * 4;
    float4 v = *(const float4*)&x[i];
    ushort4 p;
    p.x = f2bf(v.x); p.y = f2bf(v.y); p.z = f2bf(v.z); p.w = f2bf(v.w);
    *(ushort4*)&o[i] = p;
}

// ---------------------------------------------------------------------------
// Transpose weights: W[1024][N] (f32) -> Wt[Npad][1024] (bf16), zero rows N..Npad.
// ---------------------------------------------------------------------------
__global__ __launch_bounds__(256) void k_transpose_pad(
    const float* __restrict__ W, u16* __restrict__ Wt, int N, int Npad) {
    __shared__ u16 tile[32][33];
    int k0 = blockIdx.x * 32, n0 = blockIdx.y * 32;
    int tx = threadIdx.x & 31, ty = threadIdx.x >> 5;
    for (int i = ty; i < 32; i += 8) {
        int n = n0 + tx;
        tile[i][tx] = (n < N) ? f2bf(W[(size_t)(k0 + i) * N + n]) : (u16)0;
    }
    __syncthreads();
    for (int i = ty; i < 32; i += 8) {
        int n = n0 + i;
        if (n < Npad) Wt[(size_t)n * 1024 + k0 + tx] = tile[tx][i];
    }
}

// ---------------------------------------------------------------------------
// GEMM: C[M x Npad] = A[M x 1024](bf16) @ Wt[Npad x 1024](bf16)^T + bias(f32)
// mode 0: C bf16, ldc stride
// mode 1: v transposed per batch: C -> vt[b][col][s] (bf16)
// mode 2: C = acc + bias + resid(f32), bf16, ldc stride
// ---------------------------------------------------------------------------
__global__ __launch_bounds__(256) void k_gemm_bt(
    const u16* __restrict__ A, const u16* __restrict__ Wt,
    const float* __restrict__ bias, int nbias,
    const float* __restrict__ resid,
    u16* __restrict__ C, int ldc, int mode) {
    __shared__ u16 As[64 * 72];
    __shared__ u16 Bs[64 * 72];
    const int tid = threadIdx.x;
    const int m0 = blockIdx.x * 64;
    const int n0 = blockIdx.y * 64;
    const int lane = tid & 63, w = tid >> 6;
    const int ln = lane & 15, quad = lane >> 4;

    floatx4 acc[4];
    floatx4 zero = {0.f, 0.f, 0.f, 0.f};
    for (int n = 0; n < 4; n++) acc[n] = zero;

    for (int kt = 0; kt < 16; kt++) {
        __syncthreads();
        const int c0 = kt * 64;
        for (int i = tid; i < 512; i += 256) {
            int r = i >> 3, c = (i & 7) * 8;
            *(uint4*)&As[r * 72 + c] = *(const uint4*)&A [(size_t)(m0 + r) * 1024 + c0 + c];
            *(uint4*)&Bs[r * 72 + c] = *(const uint4*)&Wt[(size_t)(n0 + r) * 1024 + c0 + c];
        }
        __syncthreads();
#pragma unroll
        for (int kk = 0; kk < 64; kk += 32) {
            short8 a = *(const short8*)&As[(w * 16 + ln) * 72 + kk + quad * 8];
#pragma unroll
            for (int n = 0; n < 4; n++) {
                short8 b = *(const short8*)&Bs[(n * 16 + ln) * 72 + kk + quad * 8];
                acc[n] = __builtin_amdgcn_mfma_f32_16x16x32_bf16(a, b, acc[n], 0, 0, 0);
            }
        }
    }

    const int rbase = m0 + w * 16 + quad * 4;
#pragma unroll
    for (int n = 0; n < 4; n++) {
        const int col = n0 + n * 16 + ln;
        const float bv = (col < nbias) ? bias[col] : 0.f;
        if (mode == 1) {
            int b = rbase >> 11;
            int s = rbase & 2047;
            ushort4 pk;
            pk.x = f2bf(acc[n][0] + bv);
            pk.y = f2bf(acc[n][1] + bv);
            pk.z = f2bf(acc[n][2] + bv);
            pk.w = f2bf(acc[n][3] + bv);
            *reinterpret_cast<ushort4*>(&C[((size_t)b << 21) + ((size_t)col << 11) + s]) = pk;
        } else if (mode == 2) {
#pragma unroll
            for (int r = 0; r < 4; r++) {
                size_t idx = (size_t)(rbase + r) * ldc + col;
                C[idx] = f2bf(acc[n][r] + bv + resid[idx]);
            }
        } else {
#pragma unroll
            for (int r = 0; r < 4; r++)
                C[(size_t)(rbase + r) * ldc + col] = f2bf(acc[n][r] + bv);
        }
    }
}

// ---------------------------------------------------------------------------
// Pass 1: softmax stats.  For each (b,s): m = max_t q.k, l = sum exp(.-m)
// grid (S/64, B), block 256 (4 waves, 16 q-rows each)
// ---------------------------------------------------------------------------
__global__ __launch_bounds__(256) void k_attn_stats(
    const u16* __restrict__ qp, const u16* __restrict__ kp,
    float* __restrict__ mg, float* __restrict__ lg) {
    __shared__ u16 ks[64 * 264];
    const int tid = threadIdx.x;
    const int s0 = blockIdx.x * 64;
    const int b  = blockIdx.y;
    const int lane = tid & 63, w = tid >> 6, ln = lane & 15, quad = lane >> 4;
    const size_t base = (size_t)b * SS * KP;

    short8 qf[8];
#pragma unroll
    for (int kk = 0; kk < 8; kk++) {
        V16 t;
        t.u = *(const uint4*)&qp[base + (size_t)(s0 + w * 16 + ln) * KP + kk * 32 + quad * 8];
        qf[kk] = t.s8;
    }

    float m_run[4] = {-3e38f, -3e38f, -3e38f, -3e38f};
    float l_run[4] = {0.f, 0.f, 0.f, 0.f};
    floatx4 zero = {0.f, 0.f, 0.f, 0.f};

    for (int t0 = 0; t0 < SS; t0 += 64) {
        __syncthreads();
        for (int i = tid; i < 2048; i += 256) {
            int r = i >> 5, c = (i & 31) * 8;
            *(uint4*)&ks[r * 264 + c] = *(const uint4*)&kp[base + (size_t)(t0 + r) * KP + c];
        }
        __syncthreads();

        floatx4 sacc[4];
        for (int tt = 0; tt < 4; tt++) sacc[tt] = zero;
#pragma unroll
        for (int kk = 0; kk < 8; kk++) {
#pragma unroll
            for (int tt = 0; tt < 4; tt++) {
                short8 bf = *(const short8*)&ks[(tt * 16 + ln) * 264 + kk * 32 + quad * 8];
                sacc[tt] = __builtin_amdgcn_mfma_f32_16x16x32_bf16(qf[kk], bf, sacc[tt], 0, 0, 0);
            }
        }
#pragma unroll
        for (int r = 0; r < 4; r++) {
            float mx = fmaxf(fmaxf(sacc[0][r], sacc[1][r]), fmaxf(sacc[2][r], sacc[3][r]));
#pragma unroll
            for (int msk = 1; msk < 16; msk <<= 1) mx = fmaxf(mx, __shfl_xor(mx, msk, 64));
            float mnew = fmaxf(m_run[r], mx);
            float s = __expf(sacc[0][r] - mnew) + __expf(sacc[1][r] - mnew)
                    + __expf(sacc[2][r] - mnew) + __expf(sacc[3][r] - mnew);
#pragma unroll
            for (int msk = 1; msk < 16; msk <<= 1) s += __shfl_xor(s, msk, 64);
            l_run[r] = l_run[r] * __expf(fminf(m_run[r] - mnew, 0.f)) + s;
            m_run[r] = mnew;
        }
    }
    if (ln == 0) {
#pragma unroll
        for (int r = 0; r < 4; r++) {
            int row = s0 + w * 16 + quad * 4 + r;
            mg[b * SS + row] = m_run[r];
            lg[b * SS + row] = l_run[r];
        }
    }
}

// ---------------------------------------------------------------------------
// Pass 2: ctx[b][s][d] = sum_t exp(q.k - m)/l * v[t][d]
// grid (S/64, D/256, B), block 256.
// ---------------------------------------------------------------------------
__global__ __launch_bounds__(256) void k_attn_ctx(
    const u16* __restrict__ qp, const u16* __restrict__ kp,
    const u16* __restrict__ vt, const float* __restrict__ mg,
    const float* __restrict__ lg, u16* __restrict__ ctx) {
    __shared__ u16 kv[256 * 72];   // k tile as [64][264] then v tile as [256][72]
    __shared__ u16 Ps[64 * 72];
    const int tid = threadIdx.x;
    const int s0 = blockIdx.x * 64;
    const int d0 = blockIdx.y * 256;
    const int b  = blockIdx.z;
    const int lane = tid & 63, w = tid >> 6, ln = lane & 15, quad = lane >> 4;
    const size_t qkbase = (size_t)b * SS * KP;
    const size_t vbase  = (size_t)b * DD * SS;

    short8 qf[8];
#pragma unroll
    for (int kk = 0; kk < 8; kk++) {
        V16 t;
        t.u = *(const uint4*)&qp[qkbase + (size_t)(s0 + w * 16 + ln) * KP + kk * 32 + quad * 8];
        qf[kk] = t.s8;
    }

    float m_i[4], inv_l[4];
#pragma unroll
    for (int r = 0; r < 4; r++) {
        int row = s0 + w * 16 + quad * 4 + r;
        m_i[r]   = mg[b * SS + row];
        inv_l[r] = 1.f / fmaxf(lg[b * SS + row], 1e-20f);
    }

    floatx4 zero = {0.f, 0.f, 0.f, 0.f};
    floatx4 acc[16];
#pragma unroll
    for (int n = 0; n < 16; n++) acc[n] = zero;

    for (int t0 = 0; t0 < SS; t0 += 64) {
        __syncthreads();   // prev PV reads of kv done before restaging k
        for (int i = tid; i < 2048; i += 256) {
            int r = i >> 5, c = (i & 31) * 8;
            *(uint4*)&kv[r * 264 + c] = *(const uint4*)&kp[qkbase + (size_t)(t0 + r) * KP + c];
        }
        __syncthreads();

        floatx4 sacc[4];
        for (int tt = 0; tt < 4; tt++) sacc[tt] = zero;
#pragma unroll
        for (int kk = 0; kk < 8; kk++) {
#pragma unroll
            for (int tt = 0; tt < 4; tt++) {
                short8 bf = *(const short8*)&kv[(tt * 16 + ln) * 264 + kk * 32 + quad * 8];
                sacc[tt] = __builtin_amdgcn_mfma_f32_16x16x32_bf16(qf[kk], bf, sacc[tt], 0, 0, 0);
            }
        }
#pragma unroll
        for (int tt = 0; tt < 4; tt++) {
#pragma unroll
            for (int r = 0; r < 4; r++) {
                float p = __expf(fminf(sacc[tt][r] - m_i[r], 0.f));
                Ps[(w * 16 + quad * 4 + r) * 72 + tt * 16 + ln] = f2bf(p);
            }
        }
        __syncthreads();   // P visible; all k reads done
        for (int i = tid; i < 2048; i += 256) {
            int r = i >> 3, c = (i & 7) * 8;
            *(uint4*)&kv[r * 72 + c] = *(const uint4*)&vt[vbase + (size_t)(d0 + r) * SS + t0 + c];
        }
        __syncthreads();
#pragma unroll
        for (int kk = 0; kk < 2; kk++) {
            short8 a = *(const short8*)&Ps[(w * 16 + ln) * 72 + kk * 32 + quad * 8];
#pragma unroll
            for (int n = 0; n < 16; n++) {
                short8 bf = *(const short8*)&kv[(n * 16 + ln) * 72 + kk * 32 + quad * 8];
                acc[n] = __builtin_amdgcn_mfma_f32_16x16x32_bf16(a, bf, acc[n], 0, 0, 0);
            }
        }
    }

    const int srow = s0 + w * 16 + quad * 4;
#pragma unroll
    for (int n = 0; n < 16; n++) {
        int col = d0 + n * 16 + ln;
#pragma unroll
        for (int r = 0; r < 4; r++) {
            ctx[((size_t)b * SS + srow + r) * DD + col] = f2bf(acc[n][r] * inv_l[r]);
        }
    }
}

// ---------------------------------------------------------------------------
// LayerNorm over last dim (1024): y (bf16) -> out (f32). gamma/beta f32.
// ---------------------------------------------------------------------------
__global__ __launch_bounds__(256) void k_layernorm(
    const u16* __restrict__ y, const float* __restrict__ gamma,
    const float* __restrict__ beta, float* __restrict__ out) {
    const int tid = threadIdx.x;
    const int lane = tid & 63, w = tid >> 6;
    const size_t row = (size_t)blockIdx.x * 4 + w;
    const u16* yr = y + row * DD;

    float v[16];
#pragma unroll
    for (int j = 0; j < 2; j++) {
        V16 t;
        t.u = *(const uint4*)&yr[j * 512 + lane * 8];
#pragma unroll
        for (int e = 0; e < 8; e++) v[j * 8 + e] = bf2f(t.h[e]);
    }
    float s = 0.f, sq = 0.f;
#pragma unroll
    for (int i = 0; i < 16; i++) { s += v[i]; sq += v[i] * v[i]; }
#pragma unroll
    for (int msk = 1; msk < 64; msk <<= 1) {
        s  += __shfl_xor(s,  msk, 64);
        sq += __shfl_xor(sq, msk, 64);
    }
    float mean = s * (1.f / 1024.f);
    float var  = sq * (1.f / 1024.f) - mean * mean;
    float rstd = rsqrtf(fmaxf(var, 0.f) + 1e-12f);
#pragma unroll
    for (int j = 0; j < 2; j++) {
        int cbase = j * 512 + lane * 8;
#pragma unroll
        for (int h = 0; h < 2; h++) {
            float4 g  = *(const float4*)&gamma[cbase + h * 4];
            float4 bt = *(const float4*)&beta [cbase + h * 4];
            float4 o;
            o.x = g.x * (v[j * 8 + h * 4 + 0] - mean) * rstd + bt.x;
            o.y = g.y * (v[j * 8 + h * 4 + 1] - mean) * rstd + bt.y;
            o.z = g.z * (v[j * 8 + h * 4 + 2] - mean) * rstd + bt.z;
            o.w = g.w * (v[j * 8 + h * 4 + 3] - mean) * rstd + bt.w;
            *(float4*)&out[row * DD + cbase + h * 4] = o;
        }
    }
}

// ---------------------------------------------------------------------------
extern "C" void kernel_launch(void* const* d_in, const int* in_sizes, int n_in,
                              void* d_out, int out_size, void* d_ws, size_t ws_size,
                              hipStream_t stream) {
    const float* x     = (const float*)d_in[0];
    const float* Wq    = (const float*)d_in[2];
    const float* bq    = (const float*)d_in[3];
    const float* Wk    = (const float*)d_in[4];
    const float* bk    = (const float*)d_in[5];
    const float* Wv    = (const float*)d_in[6];
    const float* bv    = (const float*)d_in[7];
    const float* Wd    = (const float*)d_in[8];
    const float* bd    = (const float*)d_in[9];
    const float* gamma = (const float*)d_in[10];
    const float* beta  = (const float*)d_in[11];
    float* out = (float*)d_out;

    char* ws = (char*)d_ws;
    u16*   qp  = (u16*)(ws + 0);              //  8 MB  [8][2048][256]
    u16*   kp  = (u16*)(ws + 8388608);        //  8 MB
    u16*   vtr = (u16*)(ws + 16777216);       // 32 MB  [8][1024][2048]
    u16*   ctx = (u16*)(ws + 50331648);       // 32 MB  [8][2048][1024]
    u16*   x16 = (u16*)(ws + 83886080);       // 32 MB  bf16(x); later reused as y
    u16*   y   = x16;                         // alias: x16 dead after projections
    float* mg  = (float*)(ws + 117440512);    // 64 KB
    float* lg  = (float*)(ws + 117506048);    // 64 KB
    u16*   Wqt = (u16*)(ws + 117571584);      // 512 KB [256][1024]
    u16*   Wkt = (u16*)(ws + 118095872);      // 512 KB
    u16*   Wvt = (u16*)(ws + 118620160);      //   2 MB [1024][1024]
    u16*   Wdt = (u16*)(ws + 120717312);      //   2 MB

    dim3 blk(256);

    k_cast_bf16<<<dim3(16384), blk, 0, stream>>>(x, x16);

    k_transpose_pad<<<dim3(32, 8),  blk, 0, stream>>>(Wq, Wqt, KREAL, KP);
    k_transpose_pad<<<dim3(32, 8),  blk, 0, stream>>>(Wk, Wkt, KREAL, KP);
    k_transpose_pad<<<dim3(32, 32), blk, 0, stream>>>(Wv, Wvt, DD, DD);
    k_transpose_pad<<<dim3(32, 32), blk, 0, stream>>>(Wd, Wdt, DD, DD);

    k_gemm_bt<<<dim3(256, 4),  blk, 0, stream>>>(x16, Wqt, bq, KREAL, nullptr, qp, KP, 0);
    k_gemm_bt<<<dim3(256, 4),  blk, 0, stream>>>(x16, Wkt, bk, KREAL, nullptr, kp, KP, 0);
    k_gemm_bt<<<dim3(256, 16), blk, 0, stream>>>(x16, Wvt, bv, DD, nullptr, vtr, 0, 1);

    k_attn_stats<<<dim3(32, 8),    blk, 0, stream>>>(qp, kp, mg, lg);
    k_attn_ctx  <<<dim3(32, 4, 8), blk, 0, stream>>>(qp, kp, vtr, mg, lg, ctx);

    k_gemm_bt<<<dim3(256, 16), blk, 0, stream>>>(ctx, Wdt, bd, DD, x, y, DD, 2);

    k_layernorm<<<dim3(4096), blk, 0, stream>>>(y, gamma, beta, out);
}

// Round 3
// 493.382 us; speedup vs baseline: 1.6413x; 1.6413x over previous
//
#include <hip/hip_runtime.h>
#include <stdint.h>

#define BB 8
#define SS 2048
#define DD 1024
#define KREAL 204
#define KP 256
#define BM 128
#define BK 64

typedef __attribute__((ext_vector_type(8))) short short8;
typedef __attribute__((ext_vector_type(4))) float floatx4;
typedef uint16_t u16;
typedef uint32_t u32;

__device__ __forceinline__ float bf2f(u16 u) {
    union { float f; u32 i; } c; c.i = ((u32)u) << 16; return c.f;
}
__device__ __forceinline__ u16 f2bf(float f) {
    union { float f; u32 i; } c; c.f = f;
    u32 i = c.i;
    u32 r = (i + 0x7FFFu + ((i >> 16) & 1u)) >> 16;
    return (u16)r;
}

union V16 { uint4 u; short8 s8; u16 h[8]; };

// ---------------------------------------------------------------------------
// Async global->LDS, 16 B per lane. Dest must be wave-uniform base + lane*16.
// ---------------------------------------------------------------------------
#if defined(__has_builtin)
#if __has_builtin(__builtin_amdgcn_global_load_lds)
#define HAVE_GLL 1
#endif
#endif

__device__ __forceinline__ void gload16(const u16* g, u16* l) {
#ifdef HAVE_GLL
    __builtin_amdgcn_global_load_lds(
        (const __attribute__((address_space(1))) void*)(uintptr_t)g,
        (__attribute__((address_space(3))) void*)(u32)(uintptr_t)(void*)l,
        16, 0, 0);
#else
    *(uint4*)l = *(const uint4*)g;
#endif
}

// Stage a 128x64(u16) tile with XOR swizzle: logical (row, kg) at physical
// slot = kg ^ (row&7). Keeps DMA dest lane-contiguous; makes fragment
// ds_read_b128 bank-uniform (8 accesses/bank = b128 floor).
__device__ __forceinline__ void stage_tile(const u16* __restrict__ src, size_t ld,
                                           u16* lds, int tid) {
#pragma unroll
    for (int j = 0; j < 4; j++) {
        int flat = j * 256 + tid;
        int row = flat >> 3, slot = flat & 7;
        int kg = slot ^ (row & 7);
        gload16(src + (size_t)row * ld + kg * 8, lds + flat * 8);
    }
}

__device__ __forceinline__ short8 frag(const u16* lds, int row, int kslot) {
    return *(const short8*)&lds[(row << 6) + (((kslot ^ (row & 7)) & 7) << 3)];
}

// One BK=64 step: 16 ds_read_b128 + 32 MFMA per wave.
__device__ __forceinline__ void mfma_step(const u16* As, const u16* Bs,
                                          int wm, int wn, int ln, int quad,
                                          floatx4 acc[4][4]) {
#pragma unroll
    for (int kk = 0; kk < 2; kk++) {
        short8 av[4], bv[4];
#pragma unroll
        for (int mt = 0; mt < 4; mt++) av[mt] = frag(As, wm * 64 + mt * 16 + ln, kk * 4 + quad);
#pragma unroll
        for (int nt = 0; nt < 4; nt++) bv[nt] = frag(Bs, wn * 64 + nt * 16 + ln, kk * 4 + quad);
#pragma unroll
        for (int mt = 0; mt < 4; mt++)
#pragma unroll
            for (int nt = 0; nt < 4; nt++)
                acc[mt][nt] = __builtin_amdgcn_mfma_f32_16x16x32_bf16(av[mt], bv[nt], acc[mt][nt], 0, 0, 0);
    }
}

// ---------------------------------------------------------------------------
// Cast f32 -> bf16.
// ---------------------------------------------------------------------------
__global__ __launch_bounds__(256) void k_cast_bf16(
    const float* __restrict__ x, u16* __restrict__ o) {
    size_t i = ((size_t)blockIdx.x * 256 + threadIdx.x) * 4;
    float4 v = *(const float4*)&x[i];
    ushort4 p;
    p.x = f2bf(v.x); p.y = f2bf(v.y); p.z = f2bf(v.z); p.w = f2bf(v.w);
    *(ushort4*)&o[i] = p;
}

// ---------------------------------------------------------------------------
// Transpose weights: W[1024][N] (f32) -> Wt[Npad][1024] (bf16), zero-pad.
// ---------------------------------------------------------------------------
__global__ __launch_bounds__(256) void k_transpose_pad(
    const float* __restrict__ W, u16* __restrict__ Wt, int N, int Npad) {
    __shared__ u16 tile[32][33];
    int k0 = blockIdx.x * 32, n0 = blockIdx.y * 32;
    int tx = threadIdx.x & 31, ty = threadIdx.x >> 5;
    for (int i = ty; i < 32; i += 8) {
        int n = n0 + tx;
        tile[i][tx] = (n < N) ? f2bf(W[(size_t)(k0 + i) * N + n]) : (u16)0;
    }
    __syncthreads();
    for (int i = ty; i < 32; i += 8) {
        int n = n0 + i;
        if (n < Npad) Wt[(size_t)n * 1024 + k0 + tx] = tile[tx][i];
    }
}

// ---------------------------------------------------------------------------
// Projection GEMM: C[M x N] = A[M x K](bf16) @ Wt[N x K](bf16)^T + bias(f32)
// mode 0: store bf16, ldc stride. mode 1: v-transposed per batch. mode 2: +resid f32.
// grid (M/128, N/128)
// ---------------------------------------------------------------------------
__global__ __launch_bounds__(256) void k_gemm_proj(
    const u16* __restrict__ A, const u16* __restrict__ Wt,
    const float* __restrict__ bias, int nbias,
    const float* __restrict__ resid, u16* __restrict__ C,
    int ldc, int kiters, int mode) {
    __shared__ u16 As[BM * BK];
    __shared__ u16 Bs[BM * BK];
    const int tid = threadIdx.x;
    const int m0 = blockIdx.x * BM, n0 = blockIdx.y * BM;
    const int lane = tid & 63, w = tid >> 6;
    const int wm = w >> 1, wn = w & 1;
    const int ln = lane & 15, quad = lane >> 4;
    const size_t K = (size_t)kiters * BK;

    floatx4 acc[4][4];
    floatx4 zero = {0.f, 0.f, 0.f, 0.f};
#pragma unroll
    for (int mt = 0; mt < 4; mt++)
#pragma unroll
        for (int nt = 0; nt < 4; nt++) acc[mt][nt] = zero;

    const u16* Ab = A + (size_t)m0 * K;
    const u16* Bb = Wt + (size_t)n0 * K;
    for (int kt = 0; kt < kiters; kt++) {
        __syncthreads();
        stage_tile(Ab + kt * BK, K, As, tid);
        stage_tile(Bb + kt * BK, K, Bs, tid);
        __syncthreads();
        mfma_step(As, Bs, wm, wn, ln, quad, acc);
    }

#pragma unroll
    for (int mt = 0; mt < 4; mt++) {
        const int row0 = m0 + wm * 64 + mt * 16 + quad * 4;
#pragma unroll
        for (int nt = 0; nt < 4; nt++) {
            const int col = n0 + wn * 64 + nt * 16 + ln;
            const float bv = (col < nbias) ? bias[col] : 0.f;
            if (mode == 1) {
                int b = row0 >> 11, s = row0 & 2047;
                ushort4 pk;
                pk.x = f2bf(acc[mt][nt][0] + bv);
                pk.y = f2bf(acc[mt][nt][1] + bv);
                pk.z = f2bf(acc[mt][nt][2] + bv);
                pk.w = f2bf(acc[mt][nt][3] + bv);
                *reinterpret_cast<ushort4*>(&C[((size_t)b << 21) + ((size_t)col << 11) + s]) = pk;
            } else if (mode == 2) {
#pragma unroll
                for (int r = 0; r < 4; r++) {
                    size_t idx = (size_t)(row0 + r) * ldc + col;
                    C[idx] = f2bf(acc[mt][nt][r] + bv + resid[idx]);
                }
            } else {
#pragma unroll
                for (int r = 0; r < 4; r++)
                    C[(size_t)(row0 + r) * ldc + col] = f2bf(acc[mt][nt][r] + bv);
            }
        }
    }
}

// ---------------------------------------------------------------------------
// QK GEMM: P[b][s][t] = bf16(exp(q.k - 30)); row-sums l via atomics.
// grid (S/128, S/128, nbatch). qp/kp pre-offset to the batch group.
// ---------------------------------------------------------------------------
__global__ __launch_bounds__(256) void k_gemm_qk(
    const u16* __restrict__ qp, const u16* __restrict__ kp,
    u16* __restrict__ P, float* __restrict__ lg) {
    __shared__ u16 As[BM * BK];
    __shared__ u16 Bs[BM * BK];
    const int tid = threadIdx.x;
    const int s0 = blockIdx.x * BM, t0 = blockIdx.y * BM, bb = blockIdx.z;
    const int lane = tid & 63, w = tid >> 6;
    const int wm = w >> 1, wn = w & 1;
    const int ln = lane & 15, quad = lane >> 4;

    floatx4 acc[4][4];
    floatx4 zero = {0.f, 0.f, 0.f, 0.f};
#pragma unroll
    for (int mt = 0; mt < 4; mt++)
#pragma unroll
        for (int nt = 0; nt < 4; nt++) acc[mt][nt] = zero;

    const u16* Ab = qp + ((size_t)bb * SS + s0) * KP;
    const u16* Bb = kp + ((size_t)bb * SS + t0) * KP;
#pragma unroll
    for (int kt = 0; kt < KP / BK; kt++) {
        __syncthreads();
        stage_tile(Ab + kt * BK, KP, As, tid);
        stage_tile(Bb + kt * BK, KP, Bs, tid);
        __syncthreads();
        mfma_step(As, Bs, wm, wn, ln, quad, acc);
    }

    u16* Pb = P + (size_t)bb * SS * SS;
#pragma unroll
    for (int mt = 0; mt < 4; mt++) {
        const int row0 = s0 + wm * 64 + mt * 16 + quad * 4;
#pragma unroll
        for (int r = 0; r < 4; r++) {
            float rs = 0.f;
#pragma unroll
            for (int nt = 0; nt < 4; nt++) {
                const int col = t0 + wn * 64 + nt * 16 + ln;
                float p = __expf(acc[mt][nt][r] - 30.f);
                rs += p;
                Pb[(size_t)(row0 + r) * SS + col] = f2bf(p);
            }
            rs += __shfl_xor(rs, 1);
            rs += __shfl_xor(rs, 2);
            rs += __shfl_xor(rs, 4);
            rs += __shfl_xor(rs, 8);
            if (ln == 0) atomicAdd(&lg[bb * SS + row0 + r], rs);
        }
    }
}

// ---------------------------------------------------------------------------
// PV GEMM: ctx[b][s][d] = (P[b][s][:] . vt[b][d][:]) / l[b][s]
// grid (S/128, D/128, nbatch). Pointers pre-offset to the batch group.
// ---------------------------------------------------------------------------
__global__ __launch_bounds__(256) void k_gemm_pv(
    const u16* __restrict__ P, const u16* __restrict__ vt,
    const float* __restrict__ lg, u16* __restrict__ ctx) {
    __shared__ u16 As[BM * BK];
    __shared__ u16 Bs[BM * BK];
    const int tid = threadIdx.x;
    const int s0 = blockIdx.x * BM, d0 = blockIdx.y * BM, bb = blockIdx.z;
    const int lane = tid & 63, w = tid >> 6;
    const int wm = w >> 1, wn = w & 1;
    const int ln = lane & 15, quad = lane >> 4;

    floatx4 acc[4][4];
    floatx4 zero = {0.f, 0.f, 0.f, 0.f};
#pragma unroll
    for (int mt = 0; mt < 4; mt++)
#pragma unroll
        for (int nt = 0; nt < 4; nt++) acc[mt][nt] = zero;

    const u16* Ab = P + ((size_t)bb * SS + s0) * SS;
    const u16* Bb = vt + ((size_t)bb * DD + d0) * SS;
    for (int kt = 0; kt < SS / BK; kt++) {
        __syncthreads();
        stage_tile(Ab + kt * BK, SS, As, tid);
        stage_tile(Bb + kt * BK, SS, Bs, tid);
        __syncthreads();
        mfma_step(As, Bs, wm, wn, ln, quad, acc);
    }

#pragma unroll
    for (int mt = 0; mt < 4; mt++) {
        const int row0 = s0 + wm * 64 + mt * 16 + quad * 4;
#pragma unroll
        for (int r = 0; r < 4; r++) {
            const float inv = 1.f / lg[bb * SS + row0 + r];
#pragma unroll
            for (int nt = 0; nt < 4; nt++) {
                const int col = d0 + wn * 64 + nt * 16 + ln;
                ctx[((size_t)bb * SS + row0 + r) * DD + col] = f2bf(acc[mt][nt][r] * inv);
            }
        }
    }
}

// ---------------------------------------------------------------------------
// LayerNorm over last dim (1024): y (bf16) -> out (f32). gamma/beta f32.
// ---------------------------------------------------------------------------
__global__ __launch_bounds__(256) void k_layernorm(
    const u16* __restrict__ y, const float* __restrict__ gamma,
    const float* __restrict__ beta, float* __restrict__ out) {
    const int tid = threadIdx.x;
    const int lane = tid & 63, w = tid >> 6;
    const size_t row = (size_t)blockIdx.x * 4 + w;
    const u16* yr = y + row * DD;

    float v[16];
#pragma unroll
    for (int j = 0; j < 2; j++) {
        V16 t;
        t.u = *(const uint4*)&yr[j * 512 + lane * 8];
#pragma unroll
        for (int e = 0; e < 8; e++) v[j * 8 + e] = bf2f(t.h[e]);
    }
    float s = 0.f, sq = 0.f;
#pragma unroll
    for (int i = 0; i < 16; i++) { s += v[i]; sq += v[i] * v[i]; }
#pragma unroll
    for (int msk = 1; msk < 64; msk <<= 1) {
        s  += __shfl_xor(s,  msk, 64);
        sq += __shfl_xor(sq, msk, 64);
    }
    float mean = s * (1.f / 1024.f);
    float var  = sq * (1.f / 1024.f) - mean * mean;
    float rstd = rsqrtf(fmaxf(var, 0.f) + 1e-12f);
#pragma unroll
    for (int j = 0; j < 2; j++) {
        int cbase = j * 512 + lane * 8;
#pragma unroll
        for (int h = 0; h < 2; h++) {
            float4 g  = *(const float4*)&gamma[cbase + h * 4];
            float4 bt = *(const float4*)&beta [cbase + h * 4];
            float4 o;
            o.x = g.x * (v[j * 8 + h * 4 + 0] - mean) * rstd + bt.x;
            o.y = g.y * (v[j * 8 + h * 4 + 1] - mean) * rstd + bt.y;
            o.z = g.z * (v[j * 8 + h * 4 + 2] - mean) * rstd + bt.z;
            o.w = g.w * (v[j * 8 + h * 4 + 3] - mean) * rstd + bt.w;
            *(float4*)&out[row * DD + cbase + h * 4] = o;
        }
    }
}

// ---------------------------------------------------------------------------
extern "C" void kernel_launch(void* const* d_in, const int* in_sizes, int n_in,
                              void* d_out, int out_size, void* d_ws, size_t ws_size,
                              hipStream_t stream) {
    const float* x     = (const float*)d_in[0];
    const float* Wq    = (const float*)d_in[2];
    const float* bq    = (const float*)d_in[3];
    const float* Wk    = (const float*)d_in[4];
    const float* bk    = (const float*)d_in[5];
    const float* Wv    = (const float*)d_in[6];
    const float* bv    = (const float*)d_in[7];
    const float* Wd    = (const float*)d_in[8];
    const float* bd    = (const float*)d_in[9];
    const float* gamma = (const float*)d_in[10];
    const float* beta  = (const float*)d_in[11];
    float* out = (float*)d_out;

    // Workspace layout (high-water ~117 MB, proven budget >= 122.8 MB):
    //   [0,8M)    qp            (dead after QK; overlaid by y)
    //   [8M,16M)  kp            (dead after QK; overlaid by y)
    //   [16M,48M) vtr           (dead after last PV; y overlays [16M,32M))
    //   [48M,80M) x16 (dead before QK) then P (4-batch group, 32 MB)
    //   [80M,112M) ctx
    //   [112M,...) lg, transposed weights
    char* ws = (char*)d_ws;
    u16*   qp  = (u16*)(ws + 0);
    u16*   kp  = (u16*)(ws + (8u << 20));
    u16*   vtr = (u16*)(ws + (16u << 20));
    u16*   x16 = (u16*)(ws + (48u << 20));
    u16*   P   = (u16*)(ws + (48u << 20));
    u16*   ctx = (u16*)(ws + (80u << 20));
    u16*   y   = (u16*)(ws + 0);
    float* lg  = (float*)(ws + 117440512);     // 112 MB, 64 KB
    u16*   Wqt = (u16*)(ws + 117506048);       // 512 KB [256][1024]
    u16*   Wkt = (u16*)(ws + 118030336);       // 512 KB
    u16*   Wvt = (u16*)(ws + 118554624);       //   2 MB [1024][1024]
    u16*   Wdt = (u16*)(ws + 120651776);       //   2 MB (ends 122748928)

    dim3 blk(256);

    k_cast_bf16<<<dim3(16384), blk, 0, stream>>>(x, x16);

    k_transpose_pad<<<dim3(32, 8),  blk, 0, stream>>>(Wq, Wqt, KREAL, KP);
    k_transpose_pad<<<dim3(32, 8),  blk, 0, stream>>>(Wk, Wkt, KREAL, KP);
    k_transpose_pad<<<dim3(32, 32), blk, 0, stream>>>(Wv, Wvt, DD, DD);
    k_transpose_pad<<<dim3(32, 32), blk, 0, stream>>>(Wd, Wdt, DD, DD);

    // Projections (K=1024, 16 k-iters)
    k_gemm_proj<<<dim3(128, 2), blk, 0, stream>>>(x16, Wqt, bq, KREAL, nullptr, qp, KP, 16, 0);
    k_gemm_proj<<<dim3(128, 2), blk, 0, stream>>>(x16, Wkt, bk, KREAL, nullptr, kp, KP, 16, 0);
    k_gemm_proj<<<dim3(128, 8), blk, 0, stream>>>(x16, Wvt, bv, DD, nullptr, vtr, 0, 16, 1);

    hipMemsetAsync(lg, 0, (size_t)BB * SS * sizeof(float), stream);

    // Attention in 2 groups of 4 batches (P buffer reuse: 32 MB)
    for (int g = 0; g < 2; g++) {
        const size_t qo = (size_t)g * 4 * SS * KP;
        const size_t vo = (size_t)g * 4 * (size_t)DD * SS;
        const size_t co = (size_t)g * 4 * (size_t)SS * DD;
        const size_t lo = (size_t)g * 4 * SS;
        k_gemm_qk<<<dim3(16, 16, 4), blk, 0, stream>>>(qp + qo, kp + qo, P, lg + lo);
        k_gemm_pv<<<dim3(16, 8, 4),  blk, 0, stream>>>(P, vtr + vo, lg + lo, ctx + co);
    }

    // Output projection + residual -> y (bf16)
    k_gemm_proj<<<dim3(128, 8), blk, 0, stream>>>(ctx, Wdt, bd, DD, x, y, DD, 16, 2);

    k_layernorm<<<dim3(4096), blk, 0, stream>>>(y, gamma, beta, out);
}

// Round 4
// 426.047 us; speedup vs baseline: 1.9006x; 1.1580x over previous
//
#include <hip/hip_runtime.h>
#include <stdint.h>

#define BB 8
#define SS 2048
#define DD 1024
#define KREAL 204
#define KP 256
#define BM 128
#define BK 64

typedef __attribute__((ext_vector_type(8))) short short8;
typedef __attribute__((ext_vector_type(4))) float floatx4;
typedef uint16_t u16;
typedef uint32_t u32;

__device__ __forceinline__ float bf2f(u16 u) {
    union { float f; u32 i; } c; c.i = ((u32)u) << 16; return c.f;
}
__device__ __forceinline__ u16 f2bf(float f) {
    union { float f; u32 i; } c; c.f = f;
    u32 i = c.i;
    u32 r = (i + 0x7FFFu + ((i >> 16) & 1u)) >> 16;
    return (u16)r;
}

union V16 { uint4 u; short8 s8; u16 h[8]; };

#if defined(__has_builtin)
#if __has_builtin(__builtin_amdgcn_global_load_lds)
#define HAVE_GLL 1
#endif
#endif

__device__ __forceinline__ void gload16(const u16* g, u16* l) {
#ifdef HAVE_GLL
    __builtin_amdgcn_global_load_lds(
        (const __attribute__((address_space(1))) void*)(uintptr_t)g,
        (__attribute__((address_space(3))) void*)(u32)(uintptr_t)(void*)l,
        16, 0, 0);
#else
    *(uint4*)l = *(const uint4*)g;
#endif
}

// 128x64(u16) tile stage, XOR swizzle slot = kg ^ (row&7): DMA-legal
// (wave-uniform base + lane*16) and conflict-free b128 fragment reads
// (verified: SQ_LDS_BANK_CONFLICT == 0 in round 3).
__device__ __forceinline__ void stage_tile(const u16* __restrict__ src, size_t ld,
                                           u16* lds, int tid) {
#pragma unroll
    for (int j = 0; j < 4; j++) {
        int flat = j * 256 + tid;
        int row = flat >> 3, slot = flat & 7;
        int kg = slot ^ (row & 7);
        gload16(src + (size_t)row * ld + kg * 8, lds + flat * 8);
    }
}

__device__ __forceinline__ short8 frag(const u16* lds, int row, int kslot) {
    return *(const short8*)&lds[(row << 6) + (((kslot ^ (row & 7)) & 7) << 3)];
}

__device__ __forceinline__ void mfma_step(const u16* As, const u16* Bs,
                                          int wm, int wn, int ln, int quad,
                                          floatx4 acc[4][4]) {
#pragma unroll
    for (int kk = 0; kk < 2; kk++) {
        short8 av[4], bv[4];
#pragma unroll
        for (int mt = 0; mt < 4; mt++) av[mt] = frag(As, wm * 64 + mt * 16 + ln, kk * 4 + quad);
#pragma unroll
        for (int nt = 0; nt < 4; nt++) bv[nt] = frag(Bs, wn * 64 + nt * 16 + ln, kk * 4 + quad);
#pragma unroll
        for (int mt = 0; mt < 4; mt++)
#pragma unroll
            for (int nt = 0; nt < 4; nt++)
                acc[mt][nt] = __builtin_amdgcn_mfma_f32_16x16x32_bf16(av[mt], bv[nt], acc[mt][nt], 0, 0, 0);
    }
}

// ---------------------------------------------------------------------------
// Cast f32 -> bf16.
// ---------------------------------------------------------------------------
__global__ __launch_bounds__(256) void k_cast_bf16(
    const float* __restrict__ x, u16* __restrict__ o) {
    size_t i = ((size_t)blockIdx.x * 256 + threadIdx.x) * 4;
    float4 v = *(const float4*)&x[i];
    ushort4 p;
    p.x = f2bf(v.x); p.y = f2bf(v.y); p.z = f2bf(v.z); p.w = f2bf(v.w);
    *(ushort4*)&o[i] = p;
}

// ---------------------------------------------------------------------------
// Weight prep, one launch: z=0 Wq->Wqkt rows 0-255 (transposed, zero-pad),
// z=1 Wk->Wqkt rows 256-511, z=2 Wv plain cast -> Wv16, z=3 Wd->Wdt.
// ---------------------------------------------------------------------------
__global__ __launch_bounds__(256) void k_prep_weights(
    const float* __restrict__ Wq, const float* __restrict__ Wk,
    const float* __restrict__ Wv, const float* __restrict__ Wd,
    u16* __restrict__ Wqkt, u16* __restrict__ Wv16, u16* __restrict__ Wdt) {
    const int z = blockIdx.z;
    __shared__ u16 tile[32][33];
    int k0 = blockIdx.x * 32, n0 = blockIdx.y * 32;
    int tx = threadIdx.x & 31, ty = threadIdx.x >> 5;
    if (z == 2) {
        for (int i = ty; i < 32; i += 8) {
            size_t idx = (size_t)(k0 + i) * 1024 + n0 + tx;
            Wv16[idx] = f2bf(Wv[idx]);
        }
        return;
    }
    const float* W; u16* out; int N, Npad, rowoff;
    if (z == 0)      { W = Wq; out = Wqkt; N = KREAL; Npad = 256;  rowoff = 0;   }
    else if (z == 1) { W = Wk; out = Wqkt; N = KREAL; Npad = 256;  rowoff = 256; }
    else             { W = Wd; out = Wdt;  N = 1024;  Npad = 1024; rowoff = 0;   }
    if (n0 >= Npad) return;
    for (int i = ty; i < 32; i += 8) {
        int n = n0 + tx;
        tile[i][tx] = (n < N) ? f2bf(W[(size_t)(k0 + i) * N + n]) : (u16)0;
    }
    __syncthreads();
    for (int i = ty; i < 32; i += 8) {
        int n = n0 + i;
        if (n < Npad) out[(size_t)(rowoff + n) * 1024 + k0 + tx] = tile[tx][i];
    }
}

// ---------------------------------------------------------------------------
// Bias prep: bc[n] = bd[n] + sum_d bv[d]*Wd[d][n]  (blocks 0-15, 64 n each)
//            bqk[0:512] = [bq | pad | bk | pad]    (block 16)
// ---------------------------------------------------------------------------
__global__ __launch_bounds__(256) void k_prep_bias(
    const float* __restrict__ bv, const float* __restrict__ bd,
    const float* __restrict__ Wd, const float* __restrict__ bq,
    const float* __restrict__ bk, float* __restrict__ bc,
    float* __restrict__ bqk) {
    const int t = threadIdx.x;
    if (blockIdx.x < 16) {
        __shared__ float red[4][64];
        int n = blockIdx.x * 64 + (t & 63);
        int dc = t >> 6;
        float s = 0.f;
        for (int d = dc * 256; d < dc * 256 + 256; d++)
            s += bv[d] * Wd[(size_t)d * 1024 + n];
        red[dc][t & 63] = s;
        __syncthreads();
        if (dc == 0) bc[n] = bd[n] + red[0][t & 63] + red[1][t & 63] + red[2][t & 63] + red[3][t & 63];
    } else {
        for (int i = t; i < 512; i += 256) {
            float v = 0.f;
            if (i < KREAL) v = bq[i];
            else if (i >= 256 && i < 256 + KREAL) v = bk[i - 256];
            bqk[i] = v;
        }
    }
}

// ---------------------------------------------------------------------------
// GEMM engine: C[M x N] = A[M x K](bf16) @ Wt[N x K](bf16)^T + bias(f32)
// mode 0: row-major store, stride ldc
// mode 1: per-batch transposed store C[b][col][s] (b = row>>11)
// mode 3: transposed store C[col*ldc + row]
// grid (M/128, N/128)
// ---------------------------------------------------------------------------
__global__ __launch_bounds__(256) void k_gemm_proj(
    const u16* __restrict__ A, const u16* __restrict__ Wt,
    const float* __restrict__ bias, int nbias,
    u16* __restrict__ C, int ldc, int kiters, int mode) {
    __shared__ u16 As[BM * BK];
    __shared__ u16 Bs[BM * BK];
    const int tid = threadIdx.x;
    const int m0 = blockIdx.x * BM, n0 = blockIdx.y * BM;
    const int lane = tid & 63, w = tid >> 6;
    const int wm = w >> 1, wn = w & 1;
    const int ln = lane & 15, quad = lane >> 4;
    const size_t K = (size_t)kiters * BK;

    floatx4 acc[4][4];
    floatx4 zero = {0.f, 0.f, 0.f, 0.f};
#pragma unroll
    for (int mt = 0; mt < 4; mt++)
#pragma unroll
        for (int nt = 0; nt < 4; nt++) acc[mt][nt] = zero;

    const u16* Ab = A + (size_t)m0 * K;
    const u16* Bb = Wt + (size_t)n0 * K;
    for (int kt = 0; kt < kiters; kt++) {
        __syncthreads();
        stage_tile(Ab + kt * BK, K, As, tid);
        stage_tile(Bb + kt * BK, K, Bs, tid);
        __syncthreads();
        mfma_step(As, Bs, wm, wn, ln, quad, acc);
    }

#pragma unroll
    for (int mt = 0; mt < 4; mt++) {
        const int row0 = m0 + wm * 64 + mt * 16 + quad * 4;
#pragma unroll
        for (int nt = 0; nt < 4; nt++) {
            const int col = n0 + wn * 64 + nt * 16 + ln;
            const float bv = (col < nbias) ? bias[col] : 0.f;
            if (mode == 1) {
                int b = row0 >> 11, s = row0 & 2047;
                ushort4 pk;
                pk.x = f2bf(acc[mt][nt][0] + bv);
                pk.y = f2bf(acc[mt][nt][1] + bv);
                pk.z = f2bf(acc[mt][nt][2] + bv);
                pk.w = f2bf(acc[mt][nt][3] + bv);
                *reinterpret_cast<ushort4*>(&C[((size_t)b << 21) + ((size_t)col << 11) + s]) = pk;
            } else if (mode == 3) {
                ushort4 pk;
                pk.x = f2bf(acc[mt][nt][0] + bv);
                pk.y = f2bf(acc[mt][nt][1] + bv);
                pk.z = f2bf(acc[mt][nt][2] + bv);
                pk.w = f2bf(acc[mt][nt][3] + bv);
                *reinterpret_cast<ushort4*>(&C[(size_t)col * ldc + row0]) = pk;
            } else {
#pragma unroll
                for (int r = 0; r < 4; r++)
                    C[(size_t)(row0 + r) * ldc + col] = f2bf(acc[mt][nt][r] + bv);
            }
        }
    }
}

// ---------------------------------------------------------------------------
// QK GEMM: P[b][s][t] = bf16(exp(q.k - 30)); row-sums l via atomics.
// q/k packed in qkp rows of 512 (q cols 0-255, k cols 256-511).
// grid (S/128, S/128, nbatch).
// ---------------------------------------------------------------------------
__global__ __launch_bounds__(256) void k_gemm_qk(
    const u16* __restrict__ qkp, u16* __restrict__ P, float* __restrict__ lg) {
    __shared__ u16 As[BM * BK];
    __shared__ u16 Bs[BM * BK];
    const int tid = threadIdx.x;
    const int s0 = blockIdx.x * BM, t0 = blockIdx.y * BM, bb = blockIdx.z;
    const int lane = tid & 63, w = tid >> 6;
    const int wm = w >> 1, wn = w & 1;
    const int ln = lane & 15, quad = lane >> 4;

    floatx4 acc[4][4];
    floatx4 zero = {0.f, 0.f, 0.f, 0.f};
#pragma unroll
    for (int mt = 0; mt < 4; mt++)
#pragma unroll
        for (int nt = 0; nt < 4; nt++) acc[mt][nt] = zero;

    const u16* Ab = qkp + ((size_t)bb * SS + s0) * 512;
    const u16* Bb = qkp + ((size_t)bb * SS + t0) * 512 + 256;
#pragma unroll
    for (int kt = 0; kt < KP / BK; kt++) {
        __syncthreads();
        stage_tile(Ab + kt * BK, 512, As, tid);
        stage_tile(Bb + kt * BK, 512, Bs, tid);
        __syncthreads();
        mfma_step(As, Bs, wm, wn, ln, quad, acc);
    }

    u16* Pb = P + (size_t)bb * SS * SS;
#pragma unroll
    for (int mt = 0; mt < 4; mt++) {
        const int row0 = s0 + wm * 64 + mt * 16 + quad * 4;
#pragma unroll
        for (int r = 0; r < 4; r++) {
            float rs = 0.f;
#pragma unroll
            for (int nt = 0; nt < 4; nt++) {
                const int col = t0 + wn * 64 + nt * 16 + ln;
                float p = __expf(acc[mt][nt][r] - 30.f);
                rs += p;
                Pb[(size_t)(row0 + r) * SS + col] = f2bf(p);
            }
            rs += __shfl_xor(rs, 1);
            rs += __shfl_xor(rs, 2);
            rs += __shfl_xor(rs, 4);
            rs += __shfl_xor(rs, 8);
            if (ln == 0) atomicAdd(&lg[bb * SS + row0 + r], rs);
        }
    }
}

// ---------------------------------------------------------------------------
// Final GEMM: y[b][s][d] = (P[b][s][:] . ut[b][d][:]) / l[b][s] + bc[d] + x[b][s][d]
// grid (S/128, D/128, nbatch). Pointers pre-offset to the batch group.
// ---------------------------------------------------------------------------
__global__ __launch_bounds__(256) void k_gemm_h(
    const u16* __restrict__ P, const u16* __restrict__ ut,
    const float* __restrict__ lg, const float* __restrict__ bc,
    const float* __restrict__ xres, u16* __restrict__ y) {
    __shared__ u16 As[BM * BK];
    __shared__ u16 Bs[BM * BK];
    const int tid = threadIdx.x;
    const int s0 = blockIdx.x * BM, d0 = blockIdx.y * BM, bb = blockIdx.z;
    const int lane = tid & 63, w = tid >> 6;
    const int wm = w >> 1, wn = w & 1;
    const int ln = lane & 15, quad = lane >> 4;

    floatx4 acc[4][4];
    floatx4 zero = {0.f, 0.f, 0.f, 0.f};
#pragma unroll
    for (int mt = 0; mt < 4; mt++)
#pragma unroll
        for (int nt = 0; nt < 4; nt++) acc[mt][nt] = zero;

    const u16* Ab = P + ((size_t)bb * SS + s0) * SS;
    const u16* Bb = ut + ((size_t)bb * DD + d0) * SS;
    for (int kt = 0; kt < SS / BK; kt++) {
        __syncthreads();
        stage_tile(Ab + kt * BK, SS, As, tid);
        stage_tile(Bb + kt * BK, SS, Bs, tid);
        __syncthreads();
        mfma_step(As, Bs, wm, wn, ln, quad, acc);
    }

#pragma unroll
    for (int mt = 0; mt < 4; mt++) {
        const int row0 = s0 + wm * 64 + mt * 16 + quad * 4;
#pragma unroll
        for (int r = 0; r < 4; r++) {
            const size_t grow = (size_t)bb * SS + row0 + r;
            const float inv = 1.f / lg[grow];
#pragma unroll
            for (int nt = 0; nt < 4; nt++) {
                const int col = d0 + wn * 64 + nt * 16 + ln;
                y[grow * DD + col] = f2bf(acc[mt][nt][r] * inv + bc[col] + xres[grow * DD + col]);
            }
        }
    }
}

// ---------------------------------------------------------------------------
// LayerNorm over last dim (1024): y (bf16) -> out (f32). gamma/beta f32.
// ---------------------------------------------------------------------------
__global__ __launch_bounds__(256) void k_layernorm(
    const u16* __restrict__ y, const float* __restrict__ gamma,
    const float* __restrict__ beta, float* __restrict__ out) {
    const int tid = threadIdx.x;
    const int lane = tid & 63, w = tid >> 6;
    const size_t row = (size_t)blockIdx.x * 4 + w;
    const u16* yr = y + row * DD;

    float v[16];
#pragma unroll
    for (int j = 0; j < 2; j++) {
        V16 t;
        t.u = *(const uint4*)&yr[j * 512 + lane * 8];
#pragma unroll
        for (int e = 0; e < 8; e++) v[j * 8 + e] = bf2f(t.h[e]);
    }
    float s = 0.f, sq = 0.f;
#pragma unroll
    for (int i = 0; i < 16; i++) { s += v[i]; sq += v[i] * v[i]; }
#pragma unroll
    for (int msk = 1; msk < 64; msk <<= 1) {
        s  += __shfl_xor(s,  msk, 64);
        sq += __shfl_xor(sq, msk, 64);
    }
    float mean = s * (1.f / 1024.f);
    float var  = sq * (1.f / 1024.f) - mean * mean;
    float rstd = rsqrtf(fmaxf(var, 0.f) + 1e-12f);
#pragma unroll
    for (int j = 0; j < 2; j++) {
        int cbase = j * 512 + lane * 8;
#pragma unroll
        for (int h = 0; h < 2; h++) {
            float4 g  = *(const float4*)&gamma[cbase + h * 4];
            float4 bt = *(const float4*)&beta [cbase + h * 4];
            float4 o;
            o.x = g.x * (v[j * 8 + h * 4 + 0] - mean) * rstd + bt.x;
            o.y = g.y * (v[j * 8 + h * 4 + 1] - mean) * rstd + bt.y;
            o.z = g.z * (v[j * 8 + h * 4 + 2] - mean) * rstd + bt.z;
            o.w = g.w * (v[j * 8 + h * 4 + 3] - mean) * rstd + bt.w;
            *(float4*)&out[row * DD + cbase + h * 4] = o;
        }
    }
}

// ---------------------------------------------------------------------------
extern "C" void kernel_launch(void* const* d_in, const int* in_sizes, int n_in,
                              void* d_out, int out_size, void* d_ws, size_t ws_size,
                              hipStream_t stream) {
    const float* x     = (const float*)d_in[0];
    const float* Wq    = (const float*)d_in[2];
    const float* bq    = (const float*)d_in[3];
    const float* Wk    = (const float*)d_in[4];
    const float* bk    = (const float*)d_in[5];
    const float* Wv    = (const float*)d_in[6];
    const float* bv    = (const float*)d_in[7];
    const float* Wd    = (const float*)d_in[8];
    const float* bd    = (const float*)d_in[9];
    const float* gamma = (const float*)d_in[10];
    const float* beta  = (const float*)d_in[11];
    float* out = (float*)d_out;

    // Workspace (high-water ~115 MB; 122.7 MB proven usable in rounds 2-3):
    //   [0,16M)    qkp  [16384][512]  (q cols 0-255, k cols 256-511)
    //   [16M,48M)  ut   [8][1024][2048]  u = x@Wvd, V-transposed
    //   [48M,80M)  x16 (dead before QK) then P (4-batch group)
    //   [80M,112M) Wv16/Wvdt (dead before h-GEMM) then y
    //   [112M,..)  lg, bc, bqk, Wqkt, Wdt
    char* ws = (char*)d_ws;
    u16*   qkp  = (u16*)(ws + 0);
    u16*   ut   = (u16*)(ws + (16u << 20));
    u16*   x16  = (u16*)(ws + (48u << 20));
    u16*   P    = (u16*)(ws + (48u << 20));
    u16*   Wv16 = (u16*)(ws + (80u << 20));            // 2 MB, dead after Wvdt-GEMM
    u16*   Wvdt = (u16*)(ws + (80u << 20) + 2097152);  // 2 MB, dead after u-proj
    u16*   y    = (u16*)(ws + (80u << 20));            // overlays Wv16/Wvdt (both dead)
    float* lg   = (float*)(ws + 117440512);            // 64 KB
    float* bc   = (float*)(ws + 117506048);            // 4 KB
    float* bqk  = (float*)(ws + 117510144);            // 2 KB
    u16*   Wqkt = (u16*)(ws + 117512192);              // 1 MB [512][1024]
    u16*   Wdt  = (u16*)(ws + 118560768);              // 2 MB (ends ~115.1 MB)

    dim3 blk(256);

    k_cast_bf16<<<dim3(16384), blk, 0, stream>>>(x, x16);
    k_prep_weights<<<dim3(32, 32, 4), blk, 0, stream>>>(Wq, Wk, Wv, Wd, Wqkt, Wv16, Wdt);
    k_prep_bias<<<dim3(17), blk, 0, stream>>>(bv, bd, Wd, bq, bk, bc, bqk);

    // Wvdt[j][i] = sum_d Wv[i][d]*Wd[d][j]  (mode 3: transposed store)
    k_gemm_proj<<<dim3(8, 8), blk, 0, stream>>>(Wv16, Wdt, nullptr, 0, Wvdt, 1024, 16, 3);

    // q|k packed projection (N=512) and u = x@Wvd (V-transposed)
    k_gemm_proj<<<dim3(128, 4), blk, 0, stream>>>(x16, Wqkt, bqk, 512, qkp, 512, 16, 0);
    k_gemm_proj<<<dim3(128, 8), blk, 0, stream>>>(x16, Wvdt, nullptr, 0, ut, 0, 16, 1);

    hipMemsetAsync(lg, 0, (size_t)BB * SS * sizeof(float), stream);

    // Attention in 2 groups of 4 batches (P buffer reuse: 32 MB)
    for (int g = 0; g < 2; g++) {
        const size_t qo = (size_t)g * 4 * SS * 512;
        const size_t uo = (size_t)g * 4 * (size_t)DD * SS;
        const size_t yo = (size_t)g * 4 * (size_t)SS * DD;
        const size_t lo = (size_t)g * 4 * SS;
        k_gemm_qk<<<dim3(16, 16, 4), blk, 0, stream>>>(qkp + qo, P, lg + lo);
        k_gemm_h <<<dim3(16, 8, 4),  blk, 0, stream>>>(P, ut + uo, lg + lo, bc, x + yo, y + yo);
    }

    k_layernorm<<<dim3(4096), blk, 0, stream>>>(y, gamma, beta, out);
}

// Round 5
// 384.682 us; speedup vs baseline: 2.1050x; 1.1075x over previous
//
#include <hip/hip_runtime.h>
#include <stdint.h>

#define BB 8
#define SS 2048
#define DD 1024
#define KREAL 204
#define KP 256
#define BM 128
#define BK 64

typedef __attribute__((ext_vector_type(8))) short short8;
typedef __attribute__((ext_vector_type(4))) float floatx4;
typedef uint16_t u16;
typedef uint32_t u32;

__device__ __forceinline__ float bf2f(u16 u) {
    union { float f; u32 i; } c; c.i = ((u32)u) << 16; return c.f;
}
__device__ __forceinline__ u16 f2bf(float f) {
    union { float f; u32 i; } c; c.f = f;
    u32 i = c.i;
    u32 r = (i + 0x7FFFu + ((i >> 16) & 1u)) >> 16;
    return (u16)r;
}

union V16 { uint4 u; short8 s8; u16 h[8]; };

#if defined(__has_builtin)
#if __has_builtin(__builtin_amdgcn_global_load_lds)
#define HAVE_GLL 1
#endif
#endif

__device__ __forceinline__ void gload16(const u16* g, u16* l) {
#ifdef HAVE_GLL
    __builtin_amdgcn_global_load_lds(
        (const __attribute__((address_space(1))) void*)(uintptr_t)g,
        (__attribute__((address_space(3))) void*)(u32)(uintptr_t)(void*)l,
        16, 0, 0);
#else
    *(uint4*)l = *(const uint4*)g;
#endif
}

// Swizzled staging (slot = kg ^ (row&7)): DMA-legal, conflict-free b128
// fragment reads (verified: SQ_LDS_BANK_CONFLICT == 0, rounds 3-4).
__device__ __forceinline__ void stage128(const u16* __restrict__ src, size_t ld,
                                         u16* lds, int tid) {
#pragma unroll
    for (int j = 0; j < 4; j++) {
        int flat = j * 256 + tid;
        int row = flat >> 3, slot = flat & 7;
        int kg = slot ^ (row & 7);
        gload16(src + (size_t)row * ld + kg * 8, lds + flat * 8);
    }
}
__device__ __forceinline__ void stage64(const u16* __restrict__ src, size_t ld,
                                        u16* lds, int tid) {
#pragma unroll
    for (int j = 0; j < 2; j++) {
        int flat = j * 256 + tid;
        int row = flat >> 3, slot = flat & 7;
        int kg = slot ^ (row & 7);
        gload16(src + (size_t)row * ld + kg * 8, lds + flat * 8);
    }
}

__device__ __forceinline__ short8 frag(const u16* lds, int row, int kslot) {
    return *(const short8*)&lds[(row << 6) + (((kslot ^ (row & 7)) & 7) << 3)];
}

__device__ __forceinline__ void mfma_step(const u16* As, const u16* Bs,
                                          int wm, int wn, int ln, int quad,
                                          floatx4 acc[4][4]) {
#pragma unroll
    for (int kk = 0; kk < 2; kk++) {
        short8 av[4], bv[4];
#pragma unroll
        for (int mt = 0; mt < 4; mt++) av[mt] = frag(As, wm * 64 + mt * 16 + ln, kk * 4 + quad);
#pragma unroll
        for (int nt = 0; nt < 4; nt++) bv[nt] = frag(Bs, wn * 64 + nt * 16 + ln, kk * 4 + quad);
#pragma unroll
        for (int mt = 0; mt < 4; mt++)
#pragma unroll
            for (int nt = 0; nt < 4; nt++)
                acc[mt][nt] = __builtin_amdgcn_mfma_f32_16x16x32_bf16(av[mt], bv[nt], acc[mt][nt], 0, 0, 0);
    }
}

// ---------------------------------------------------------------------------
// Row-major 128x128 bf16 tile store via LDS bounce (half-tiles by wm):
// every global store is a contiguous dwordx4 -> no write amplification.
// smem needs 64*136 u16 = 17 KB (aliased over staging LDS).
// ---------------------------------------------------------------------------
template <typename F>
__device__ __forceinline__ void store_rowmajor_128(
    u16* smem, u16* gbase, size_t ldc, int wm, int quad, int ln, int wn,
    int tid, F valfn) {
    for (int half = 0; half < 2; half++) {
        __syncthreads();
        if (wm == half) {
#pragma unroll
            for (int mt = 0; mt < 4; mt++)
#pragma unroll
                for (int nt = 0; nt < 4; nt++)
#pragma unroll
                    for (int r = 0; r < 4; r++)
                        smem[(mt * 16 + quad * 4 + r) * 136 + wn * 64 + nt * 16 + ln] =
                            valfn(mt, nt, r);
        }
        __syncthreads();
#pragma unroll
        for (int it = 0; it < 4; it++) {
            int g = it * 256 + tid;
            int row = g >> 4, tch = g & 15;
            uint4 v = *(const uint4*)&smem[row * 136 + tch * 8];
            *(uint4*)&gbase[(size_t)(half * 64 + row) * ldc + tch * 8] = v;
        }
    }
}

// Transposed store: C[col][row], halves by wn. Same bounce idea.
template <typename F4>
__device__ __forceinline__ void store_transposed_128(
    u16* smem, u16* gbase, size_t ldg, int wm, int wn, int ln, int quad,
    int tid, F4 valfn4) {
    for (int half = 0; half < 2; half++) {
        __syncthreads();
        if (wn == half) {
#pragma unroll
            for (int mt = 0; mt < 4; mt++)
#pragma unroll
                for (int nt = 0; nt < 4; nt++) {
                    ushort4 v = valfn4(mt, nt);
                    *(ushort4*)&smem[(nt * 16 + ln) * 136 + wm * 64 + mt * 16 + quad * 4] = v;
                }
        }
        __syncthreads();
#pragma unroll
        for (int it = 0; it < 4; it++) {
            int g = it * 256 + tid;
            int c = g >> 4, sch = g & 15;
            uint4 v = *(const uint4*)&smem[c * 136 + sch * 8];
            *(uint4*)&gbase[(size_t)(half * 64 + c) * ldg + sch * 8] = v;
        }
    }
}

// ---------------------------------------------------------------------------
// Cast f32 -> bf16.
// ---------------------------------------------------------------------------
__global__ __launch_bounds__(256) void k_cast_bf16(
    const float* __restrict__ x, u16* __restrict__ o) {
    size_t i = ((size_t)blockIdx.x * 256 + threadIdx.x) * 4;
    float4 v = *(const float4*)&x[i];
    ushort4 p;
    p.x = f2bf(v.x); p.y = f2bf(v.y); p.z = f2bf(v.z); p.w = f2bf(v.w);
    *(ushort4*)&o[i] = p;
}

// ---------------------------------------------------------------------------
// Prep (one launch): z=0 Wq->Wqkt rows 0-255, z=1 Wk->Wqkt rows 256-511,
// z=2 Wv cast -> Wv16, z=3 Wd->Wdt, z=4 bias prep (17 active blocks).
// ---------------------------------------------------------------------------
__global__ __launch_bounds__(256) void k_prep(
    const float* __restrict__ Wq, const float* __restrict__ Wk,
    const float* __restrict__ Wv, const float* __restrict__ Wd,
    const float* __restrict__ bv, const float* __restrict__ bd,
    const float* __restrict__ bq, const float* __restrict__ bk,
    u16* __restrict__ Wqkt, u16* __restrict__ Wv16, u16* __restrict__ Wdt,
    float* __restrict__ bc, float* __restrict__ bqk) {
    const int z = blockIdx.z;
    const int t = threadIdx.x;
    if (z == 4) {
        int id = blockIdx.y * 32 + blockIdx.x;
        if (id < 16) {
            __shared__ float red[4][64];
            int n = id * 64 + (t & 63);
            int dc = t >> 6;
            float s = 0.f;
            for (int d = dc * 256; d < dc * 256 + 256; d++)
                s += bv[d] * Wd[(size_t)d * 1024 + n];
            red[dc][t & 63] = s;
            __syncthreads();
            if (dc == 0) bc[n] = bd[n] + red[0][t & 63] + red[1][t & 63] + red[2][t & 63] + red[3][t & 63];
        } else if (id == 16) {
            for (int i = t; i < 512; i += 256) {
                float v = 0.f;
                if (i < KREAL) v = bq[i];
                else if (i >= 256 && i < 256 + KREAL) v = bk[i - 256];
                bqk[i] = v;
            }
        }
        return;
    }
    __shared__ u16 tile[32][33];
    int k0 = blockIdx.x * 32, n0 = blockIdx.y * 32;
    int tx = t & 31, ty = t >> 5;
    if (z == 2) {
        for (int i = ty; i < 32; i += 8) {
            size_t idx = (size_t)(k0 + i) * 1024 + n0 + tx;
            Wv16[idx] = f2bf(Wv[idx]);
        }
        return;
    }
    const float* W; u16* out; int N, Npad, rowoff;
    if (z == 0)      { W = Wq; out = Wqkt; N = KREAL; Npad = 256;  rowoff = 0;   }
    else if (z == 1) { W = Wk; out = Wqkt; N = KREAL; Npad = 256;  rowoff = 256; }
    else             { W = Wd; out = Wdt;  N = 1024;  Npad = 1024; rowoff = 0;   }
    if (n0 >= Npad) return;
    for (int i = ty; i < 32; i += 8) {
        int n = n0 + tx;
        tile[i][tx] = (n < N) ? f2bf(W[(size_t)(k0 + i) * N + n]) : (u16)0;
    }
    __syncthreads();
    for (int i = ty; i < 32; i += 8) {
        int n = n0 + i;
        if (n < Npad) out[(size_t)(rowoff + n) * 1024 + k0 + tx] = tile[tx][i];
    }
}

// ---------------------------------------------------------------------------
// Small GEMM (64x64 tiles): Wvdt[j][i] = sum_k Wv[i][k]*Wd[k][j].
// grid (16,16) = 256 blocks (the 128-tile version ran only 64 blocks).
// ---------------------------------------------------------------------------
__global__ __launch_bounds__(256) void k_gemm64(
    const u16* __restrict__ A, const u16* __restrict__ Bt,
    u16* __restrict__ C, int ldc) {
    __shared__ u16 As[64 * 64];
    __shared__ u16 Bs[64 * 64];
    const int tid = threadIdx.x;
    const int m0 = blockIdx.x * 64, n0 = blockIdx.y * 64;
    const int lane = tid & 63, w = tid >> 6;
    const int ln = lane & 15, quad = lane >> 4;

    floatx4 acc[4];
    floatx4 zero = {0.f, 0.f, 0.f, 0.f};
#pragma unroll
    for (int nt = 0; nt < 4; nt++) acc[nt] = zero;

    for (int kt = 0; kt < 16; kt++) {
        __syncthreads();
        stage64(A + (size_t)m0 * 1024 + kt * 64, 1024, As, tid);
        stage64(Bt + (size_t)n0 * 1024 + kt * 64, 1024, Bs, tid);
        __syncthreads();
#pragma unroll
        for (int kk = 0; kk < 2; kk++) {
            short8 av = frag(As, w * 16 + ln, kk * 4 + quad);
#pragma unroll
            for (int nt = 0; nt < 4; nt++) {
                short8 bvf = frag(Bs, nt * 16 + ln, kk * 4 + quad);
                acc[nt] = __builtin_amdgcn_mfma_f32_16x16x32_bf16(av, bvf, acc[nt], 0, 0, 0);
            }
        }
    }
    const int row0 = m0 + w * 16 + quad * 4;
#pragma unroll
    for (int nt = 0; nt < 4; nt++) {
        const int col = n0 + nt * 16 + ln;
        ushort4 pk;
        pk.x = f2bf(acc[nt][0]); pk.y = f2bf(acc[nt][1]);
        pk.z = f2bf(acc[nt][2]); pk.w = f2bf(acc[nt][3]);
        *reinterpret_cast<ushort4*>(&C[(size_t)col * ldc + row0]) = pk;
    }
}

// ---------------------------------------------------------------------------
// Merged projection: A = x16 [16384 x 1024].
// by<4:  qk region, B=Wqkt, cols by*128, +bqk bias -> qkp row-major (ld 512)
// by>=4: u region,  B=Wvdt, cols (by-4)*128   -> ut[b][col][s] transposed
// grid (128, 12).
// ---------------------------------------------------------------------------
__global__ __launch_bounds__(256) void k_proj(
    const u16* __restrict__ A, const u16* __restrict__ Wqkt,
    const u16* __restrict__ Wvdt, const float* __restrict__ bqk,
    u16* __restrict__ qkp, u16* __restrict__ ut) {
    __shared__ u16 smem[2 * BM * BK];
    u16* As = smem; u16* Bs = smem + BM * BK;
    const int tid = threadIdx.x;
    const int m0 = blockIdx.x * BM;
    const int by = blockIdx.y;
    const int lane = tid & 63, w = tid >> 6;
    const int wm = w >> 1, wn = w & 1;
    const int ln = lane & 15, quad = lane >> 4;

    const int n0 = (by < 4) ? by * 128 : (by - 4) * 128;
    const u16* Bb = (by < 4) ? (Wqkt + (size_t)n0 * 1024) : (Wvdt + (size_t)n0 * 1024);

    floatx4 acc[4][4];
    floatx4 zero = {0.f, 0.f, 0.f, 0.f};
#pragma unroll
    for (int mt = 0; mt < 4; mt++)
#pragma unroll
        for (int nt = 0; nt < 4; nt++) acc[mt][nt] = zero;

    const u16* Ab = A + (size_t)m0 * 1024;
    for (int kt = 0; kt < 16; kt++) {
        __syncthreads();
        stage128(Ab + kt * BK, 1024, As, tid);
        stage128(Bb + kt * BK, 1024, Bs, tid);
        __syncthreads();
        mfma_step(As, Bs, wm, wn, ln, quad, acc);
    }

    if (by < 4) {
        u16* gbase = qkp + (size_t)m0 * 512 + n0;
        store_rowmajor_128(smem, gbase, 512, wm, quad, ln, wn, tid,
            [&](int mt, int nt, int r) -> u16 {
                int col = n0 + wn * 64 + nt * 16 + ln;
                return f2bf(acc[mt][nt][r] + bqk[col]);
            });
    } else {
        int b = m0 >> 11, s0loc = m0 & 2047;
        u16* gbase = ut + ((size_t)b * DD + n0) * SS + s0loc;
        store_transposed_128(smem, gbase, SS, wm, wn, ln, quad, tid,
            [&](int mt, int nt) -> ushort4 {
                ushort4 pk;
                pk.x = f2bf(acc[mt][nt][0]); pk.y = f2bf(acc[mt][nt][1]);
                pk.z = f2bf(acc[mt][nt][2]); pk.w = f2bf(acc[mt][nt][3]);
                return pk;
            });
    }
}

// ---------------------------------------------------------------------------
// QK GEMM: P[b][s][t] = bf16(exp(q.k - 30)); row-sums l via atomics.
// grid (S/128, S/128, 4).
// ---------------------------------------------------------------------------
__global__ __launch_bounds__(256) void k_gemm_qk(
    const u16* __restrict__ qkp, u16* __restrict__ P, float* __restrict__ lg) {
    __shared__ u16 smem[2 * BM * BK];
    u16* As = smem; u16* Bs = smem + BM * BK;
    const int tid = threadIdx.x;
    const int s0 = blockIdx.x * BM, t0 = blockIdx.y * BM, bb = blockIdx.z;
    const int lane = tid & 63, w = tid >> 6;
    const int wm = w >> 1, wn = w & 1;
    const int ln = lane & 15, quad = lane >> 4;

    floatx4 acc[4][4];
    floatx4 zero = {0.f, 0.f, 0.f, 0.f};
#pragma unroll
    for (int mt = 0; mt < 4; mt++)
#pragma unroll
        for (int nt = 0; nt < 4; nt++) acc[mt][nt] = zero;

    const u16* Ab = qkp + ((size_t)bb * SS + s0) * 512;
    const u16* Bb = qkp + ((size_t)bb * SS + t0) * 512 + 256;
#pragma unroll
    for (int kt = 0; kt < KP / BK; kt++) {
        __syncthreads();
        stage128(Ab + kt * BK, 512, As, tid);
        stage128(Bb + kt * BK, 512, Bs, tid);
        __syncthreads();
        mfma_step(As, Bs, wm, wn, ln, quad, acc);
    }

    // row sums (from f32 values) -> atomics
#pragma unroll
    for (int mt = 0; mt < 4; mt++) {
        const int row0 = s0 + wm * 64 + mt * 16 + quad * 4;
#pragma unroll
        for (int r = 0; r < 4; r++) {
            float rs = __expf(acc[mt][0][r] - 30.f) + __expf(acc[mt][1][r] - 30.f)
                     + __expf(acc[mt][2][r] - 30.f) + __expf(acc[mt][3][r] - 30.f);
            rs += __shfl_xor(rs, 1);
            rs += __shfl_xor(rs, 2);
            rs += __shfl_xor(rs, 4);
            rs += __shfl_xor(rs, 8);
            if (ln == 0) atomicAdd(&lg[bb * SS + row0 + r], rs);
        }
    }

    u16* gbase = P + (size_t)bb * SS * SS + (size_t)s0 * SS + t0;
    store_rowmajor_128(smem, gbase, SS, wm, quad, ln, wn, tid,
        [&](int mt, int nt, int r) -> u16 {
            return f2bf(__expf(acc[mt][nt][r] - 30.f));
        });
}

// ---------------------------------------------------------------------------
// Final GEMM: y[b][s][d] = (P . ut)/l + bc[d] + x[b][s][d]
// grid (S/128, D/128, 4).
// ---------------------------------------------------------------------------
__global__ __launch_bounds__(256) void k_gemm_h(
    const u16* __restrict__ P, const u16* __restrict__ ut,
    const float* __restrict__ lg, const float* __restrict__ bc,
    const float* __restrict__ xres, u16* __restrict__ y) {
    __shared__ u16 smem[2 * BM * BK];
    u16* As = smem; u16* Bs = smem + BM * BK;
    const int tid = threadIdx.x;
    const int s0 = blockIdx.x * BM, d0 = blockIdx.y * BM, bb = blockIdx.z;
    const int lane = tid & 63, w = tid >> 6;
    const int wm = w >> 1, wn = w & 1;
    const int ln = lane & 15, quad = lane >> 4;

    floatx4 acc[4][4];
    floatx4 zero = {0.f, 0.f, 0.f, 0.f};
#pragma unroll
    for (int mt = 0; mt < 4; mt++)
#pragma unroll
        for (int nt = 0; nt < 4; nt++) acc[mt][nt] = zero;

    const u16* Ab = P + ((size_t)bb * SS + s0) * SS;
    const u16* Bb = ut + ((size_t)bb * DD + d0) * SS;
    for (int kt = 0; kt < SS / BK; kt++) {
        __syncthreads();
        stage128(Ab + kt * BK, SS, As, tid);
        stage128(Bb + kt * BK, SS, Bs, tid);
        __syncthreads();
        mfma_step(As, Bs, wm, wn, ln, quad, acc);
    }

    u16* gbase = y + ((size_t)bb * SS + s0) * DD + d0;
    store_rowmajor_128(smem, gbase, DD, wm, quad, ln, wn, tid,
        [&](int mt, int nt, int r) -> u16 {
            int rowl = wm * 64 + mt * 16 + quad * 4 + r;
            size_t grow = (size_t)bb * SS + s0 + rowl;
            int col = d0 + wn * 64 + nt * 16 + ln;
            float inv = 1.f / lg[grow];
            return f2bf(acc[mt][nt][r] * inv + bc[col] + xres[grow * DD + col]);
        });
}

// ---------------------------------------------------------------------------
// LayerNorm over last dim (1024): y (bf16) -> out (f32).
// ---------------------------------------------------------------------------
__global__ __launch_bounds__(256) void k_layernorm(
    const u16* __restrict__ y, const float* __restrict__ gamma,
    const float* __restrict__ beta, float* __restrict__ out) {
    const int tid = threadIdx.x;
    const int lane = tid & 63, w = tid >> 6;
    const size_t row = (size_t)blockIdx.x * 4 + w;
    const u16* yr = y + row * DD;

    float v[16];
#pragma unroll
    for (int j = 0; j < 2; j++) {
        V16 t;
        t.u = *(const uint4*)&yr[j * 512 + lane * 8];
#pragma unroll
        for (int e = 0; e < 8; e++) v[j * 8 + e] = bf2f(t.h[e]);
    }
    float s = 0.f, sq = 0.f;
#pragma unroll
    for (int i = 0; i < 16; i++) { s += v[i]; sq += v[i] * v[i]; }
#pragma unroll
    for (int msk = 1; msk < 64; msk <<= 1) {
        s  += __shfl_xor(s,  msk, 64);
        sq += __shfl_xor(sq, msk, 64);
    }
    float mean = s * (1.f / 1024.f);
    float var  = sq * (1.f / 1024.f) - mean * mean;
    float rstd = rsqrtf(fmaxf(var, 0.f) + 1e-12f);
#pragma unroll
    for (int j = 0; j < 2; j++) {
        int cbase = j * 512 + lane * 8;
#pragma unroll
        for (int h = 0; h < 2; h++) {
            float4 g  = *(const float4*)&gamma[cbase + h * 4];
            float4 bt = *(const float4*)&beta [cbase + h * 4];
            float4 o;
            o.x = g.x * (v[j * 8 + h * 4 + 0] - mean) * rstd + bt.x;
            o.y = g.y * (v[j * 8 + h * 4 + 1] - mean) * rstd + bt.y;
            o.z = g.z * (v[j * 8 + h * 4 + 2] - mean) * rstd + bt.z;
            o.w = g.w * (v[j * 8 + h * 4 + 3] - mean) * rstd + bt.w;
            *(float4*)&out[row * DD + cbase + h * 4] = o;
        }
    }
}

// ---------------------------------------------------------------------------
extern "C" void kernel_launch(void* const* d_in, const int* in_sizes, int n_in,
                              void* d_out, int out_size, void* d_ws, size_t ws_size,
                              hipStream_t stream) {
    const float* x     = (const float*)d_in[0];
    const float* Wq    = (const float*)d_in[2];
    const float* bq    = (const float*)d_in[3];
    const float* Wk    = (const float*)d_in[4];
    const float* bk    = (const float*)d_in[5];
    const float* Wv    = (const float*)d_in[6];
    const float* bv    = (const float*)d_in[7];
    const float* Wd    = (const float*)d_in[8];
    const float* bd    = (const float*)d_in[9];
    const float* gamma = (const float*)d_in[10];
    const float* beta  = (const float*)d_in[11];
    float* out = (float*)d_out;

    // Workspace (high-water ~115 MB; 122.7 MB proven usable):
    //   [0,16M)    qkp  [16384][512]
    //   [16M,48M)  ut   [8][1024][2048]
    //   [48M,80M)  x16 (dead before QK) then P (4-batch group)
    //   [80M,112M) Wv16/Wvdt (dead before h) then y
    //   [112M,..)  lg, bc, bqk, Wqkt, Wdt
    char* ws = (char*)d_ws;
    u16*   qkp  = (u16*)(ws + 0);
    u16*   ut   = (u16*)(ws + (16u << 20));
    u16*   x16  = (u16*)(ws + (48u << 20));
    u16*   P    = (u16*)(ws + (48u << 20));
    u16*   Wv16 = (u16*)(ws + (80u << 20));
    u16*   Wvdt = (u16*)(ws + (80u << 20) + 2097152);
    u16*   y    = (u16*)(ws + (80u << 20));
    float* lg   = (float*)(ws + 117440512);
    float* bc   = (float*)(ws + 117506048);
    float* bqk  = (float*)(ws + 117510144);
    u16*   Wqkt = (u16*)(ws + 117512192);
    u16*   Wdt  = (u16*)(ws + 118560768);

    dim3 blk(256);

    k_cast_bf16<<<dim3(16384), blk, 0, stream>>>(x, x16);
    k_prep<<<dim3(32, 32, 5), blk, 0, stream>>>(Wq, Wk, Wv, Wd, bv, bd, bq, bk,
                                                Wqkt, Wv16, Wdt, bc, bqk);

    // Wvd = Wv@Wd, stored transposed (256-block small-tile engine)
    k_gemm64<<<dim3(16, 16), blk, 0, stream>>>(Wv16, Wdt, Wvdt, 1024);

    // merged q|k and u projections
    k_proj<<<dim3(128, 12), blk, 0, stream>>>(x16, Wqkt, Wvdt, bqk, qkp, ut);

    hipMemsetAsync(lg, 0, (size_t)BB * SS * sizeof(float), stream);

    for (int g = 0; g < 2; g++) {
        const size_t qo = (size_t)g * 4 * SS * 512;
        const size_t uo = (size_t)g * 4 * (size_t)DD * SS;
        const size_t yo = (size_t)g * 4 * (size_t)SS * DD;
        const size_t lo = (size_t)g * 4 * SS;
        k_gemm_qk<<<dim3(16, 16, 4), blk, 0, stream>>>(qkp + qo, P, lg + lo);
        k_gemm_h <<<dim3(16, 8, 4),  blk, 0, stream>>>(P, ut + uo, lg + lo, bc, x + yo, y + yo);
    }

    k_layernorm<<<dim3(4096), blk, 0, stream>>>(y, gamma, beta, out);
}